// Round 8
// baseline (155.807 us; speedup 1.0000x reference)
//
#include <hip/hip_runtime.h>
#include <hip/hip_bf16.h>

#define BATCH   16384
#define NSTEPS  100
#define DT_     0.01f
#define SQRTDT  0.1f
#define SIGMA0_ 0.5f

typedef _Float16  f16x2  __attribute__((ext_vector_type(2)));
typedef _Float16  f16x4  __attribute__((ext_vector_type(4)));
typedef _Float16  f16x8  __attribute__((ext_vector_type(8)));
typedef __fp16    h16x2  __attribute__((ext_vector_type(2)));
typedef float     f32x4  __attribute__((ext_vector_type(4)));

typedef const __attribute__((address_space(1))) void* gas_ptr;
typedef __attribute__((address_space(3))) void*       las_ptr;

__global__ void zero_out_kernel(float* out) { if (threadIdx.x == 0) out[0] = 0.0f; }

static __device__ __forceinline__ f16x4 pk4(const f32x4& d) {
    union { h16x2 h[2]; f16x4 v; } c;
    c.h[0] = __builtin_amdgcn_cvt_pkrtz(d[0], d[1]);
    c.h[1] = __builtin_amdgcn_cvt_pkrtz(d[2], d[3]);
    return c.v;
}

// R8 = R7 decoupled split + SIMD role-mixing + q-prio + z pair-interleave.
//  - R7 counter autopsy: role bit (w>=2) put both z-waves of a CU's two
//    blocks on the same SIMDs -> q-SIMDs chain-bound, z-SIMDs poll-idle.
//    Fix: role = (w&1) ^ flip(block), flip = ((bid>>3)^(bid>>8))&1 -- co-
//    resident blocks differ by 8 (XCD fill) or 256 (sweep), so each SIMD
//    hosts one z-wave + one q-wave.
//  - q-wave runs at s_setprio(1): its serial y-recurrence is the critical
//    path; z (independent steps, prefetched y) soaks remaining slots.
//  - z processes TWO steps per body, source-interleaved (steps are data-
//    independent given the y-ring) -> 2x intra-wave ILP.
// Math identical to R7: Yv_N = Y0 + SUM(-.5 q^2 dt) + SUM(z.dw); residual
// needs no q; y published via full-depth ring, flag every 4 steps.
__launch_bounds__(256, 2)
__global__ void deepbsde_kernel(
    const float* __restrict__ y0,  const float* __restrict__ Y0,
    const float* __restrict__ zW1, const float* __restrict__ zb1,
    const float* __restrict__ zW2, const float* __restrict__ zb2,
    const float* __restrict__ zW3, const float* __restrict__ zb3,
    const float* __restrict__ qW1, const float* __restrict__ qb1,
    const float* __restrict__ qW2, const float* __restrict__ qb2,
    const float* __restrict__ qW3, const float* __restrict__ qb3,
    const float* __restrict__ dW,  const float* __restrict__ dZ,
    float* __restrict__ out)
{
    __shared__ __align__(16) char zring[2][8][384];       // [group][slot][16p * 24B]
    __shared__ __align__(16) char qring[2][8][192];       // [group][slot][16p * 12B] dW only
    __shared__ __align__(16) _Float16 tbl[NSTEPS * 128];  // [step][q4][16 f16x2]
    __shared__ float yring[2][NSTEPS + 1][16];            // full-depth y history
    __shared__ float ffin[2][16];                         // q-wave Facc finals
    __shared__ int   flags[2][2];                         // [g][0]=q progress flag

    const int tid  = threadIdx.x;
    const int lane = tid & 63;
    const int w    = tid >> 6;        // 0..3
    const int g    = w >> 1;          // waves 0,1 -> group 0; 2,3 -> group 1
    const int flip = (((int)blockIdx.x >> 3) ^ ((int)blockIdx.x >> 8)) & 1;
    const bool isQ = ((w & 1) ^ flip) != 0;
    const int ln15 = lane & 15, q4 = lane >> 4;
    const int gw   = (blockIdx.x << 1) + g;
    const int pbase = gw << 4;        // 16 paths per group

    if (tid < 4) ((int*)flags)[tid] = 0;

    auto fillz = [&](int i) {
        if (lane < 24) {
            const char* gp = (lane < 12)
                ? (const char*)dW + ((size_t)i * BATCH + pbase) * 12 + (size_t)lane * 16
                : (const char*)dZ + ((size_t)i * BATCH + pbase) * 12 + (size_t)(lane - 12) * 16;
            __builtin_amdgcn_global_load_lds((gas_ptr)gp, (las_ptr)&zring[g][i & 7][0],
                                             16, 0, 0);
        }
    };
    auto fillq = [&](int i) {
        if (lane < 12) {
            const char* gp = (const char*)dW + ((size_t)i * BATCH + pbase) * 12 + (size_t)lane * 16;
            __builtin_amdgcn_global_load_lds((gas_ptr)gp, (las_ptr)&qring[g][i & 7][0],
                                             16, 0, 0);
        }
    };
    if (!isQ) { fillz(0); fillz(1); fillz(2); fillz(3); }
    else      { fillq(0); fillq(1); fillq(2); fillq(3); }

    // ---- one-time t-table (both MLP halves), identical arithmetic ----
    {
        float tt = 0.0f;
        for (int i = 0; i < NSTEPS; ++i) {
            int r = (tid - (i << 6)) & 255;
            if (r < 64) {
                int q4e = r >> 4, mlp_ = (r >> 3) & 1, m = r & 7;
                const float* Wp = mlp_ ? qW1 : zW1;
                const float* bp = mlp_ ? qb1 : zb1;
                int i0 = 2*m, i1 = 2*m + 1;
                int k0 = 32*(i0 >> 3) + 8*q4e + (i0 & 7);
                int k1 = 32*(i1 >> 3) + 8*q4e + (i1 & 7);
                _Float16 th = (_Float16)tt;
                f16x2 A = {(_Float16)Wp[k0], (_Float16)Wp[k1]};
                f16x2 C = {(_Float16)bp[k0], (_Float16)bp[k1]};
                f16x2 tv = {th, th};
                f16x2 v = A*tv + C;
                int idx = (i*4 + q4e)*16 + mlp_*8 + m;
                *(f16x2*)&tbl[idx << 1] = v;
            }
            tt += DT_;
        }
    }

    // ---- role-selected weights ----
    const float* W1p = isQ ? qW1 : zW1;
    const float* W2p = isQ ? qW2 : zW2;
    const float* b2p = isQ ? qb2 : zb2;

    f16x2 B1[8];
#pragma unroll
    for (int m = 0; m < 8; ++m) {
        int i0 = 2*m, i1 = 2*m + 1;
        int k0 = 32*(i0 >> 3) + 8*q4 + (i0 & 7);
        int k1 = 32*(i1 >> 3) + 8*q4 + (i1 & 7);
        B1[m] = (f16x2){(_Float16)W1p[64 + k0], (_Float16)W1p[64 + k1]};
    }

    f16x8 Af[4][2];
#pragma unroll
    for (int tN = 0; tN < 4; ++tN)
#pragma unroll
        for (int f = 0; f < 2; ++f)
#pragma unroll
            for (int j = 0; j < 8; ++j) {
                int k = 32*f + 8*q4 + j, n = 16*tN + ln15;
                Af[tN][f][j] = (_Float16)W2p[k*64 + n];
            }

    f32x4 b2v[4];
#pragma unroll
    for (int tN = 0; tN < 4; ++tN)
#pragma unroll
        for (int r = 0; r < 4; ++r)
            b2v[tN][r] = b2p[16*tN + 4*q4 + r];

    const int c3 = ln15 & 3;
    f16x8 A3[2];
#pragma unroll
    for (int fl = 0; fl < 2; ++fl)
#pragma unroll
        for (int j = 0; j < 8; ++j) {
            int tN = 2*fl + (j >> 2);
            int n  = 16*tN + 4*q4 + (j & 3);
            float wv = isQ ? ((c3 == 3) ? qW3[n]                 : 0.0f)
                           : ((c3 < 3)  ? SQRTDT * zW3[n*3 + c3] : 0.0f);
            A3[fl][j] = (_Float16)wv;
        }

    const f32x4 C3b = isQ ? (f32x4){0.0f, 0.0f, 0.0f, qb3[0]}
                          : (f32x4){SQRTDT*zb3[0], SQRTDT*zb3[1], SQRTDT*zb3[2], 0.0f};

    const float CSIG = SIGMA0_ * SQRTDT;
    const float NHDT = -0.5f * DT_;
    const float y0v = y0[0], Y0v = Y0[0];

    const f16x2 zero2h = {(_Float16)0.0f, (_Float16)0.0f};
    const f16x4 zero4h = {(_Float16)0.0f, (_Float16)0.0f, (_Float16)0.0f, (_Float16)0.0f};

    // seed y(0) so z batches are uniform
    if (isQ && q4 == 0) *(volatile float*)&yring[g][0][ln15] = y0v;

    __syncthreads();   // table + flags + y0 visible; ONLY block-wide sync

    if (!isQ) {
        // ========== z-wave: independent steps, pair-interleaved ==========
        float Ysum = 0.0f, acc = 0.0f;
        float ya, yb, yc, yd;

        auto ybatch = [&](int base) {  // reads y(base..base+3); needs flag >= base+4
            volatile int* qf = &flags[g][0];
            while (*qf < base + 4) { }
            ya = *(volatile float*)&yring[g][base + 0][ln15];
            yb = *(volatile float*)&yring[g][base + 1][ln15];
            yc = *(volatile float*)&yring[g][base + 2][ln15];
            yd = *(volatile float*)&yring[g][base + 3][ln15];
        };

        auto zpair = [&](int iA, float yA, int iB, float yB) {
            const float* sA = (const float*)&zring[g][iA & 7][0];
            const float* sB = (const float*)&zring[g][iB & 7][0];
            float aw0 = sA[ln15*3+0], aw1 = sA[ln15*3+1], aw2 = sA[ln15*3+2];
            float az0 = sA[48+ln15*3+0], az1 = sA[48+ln15*3+1], az2 = sA[48+ln15*3+2];
            float bw0 = sB[ln15*3+0], bw1 = sB[ln15*3+1], bw2 = sB[ln15*3+2];
            float bz0_ = sB[48+ln15*3+0], bz1_ = sB[48+ln15*3+1], bz2_ = sB[48+ln15*3+2];

            const f16x8* tpA = (const f16x8*)(tbl + (iA*4 + q4)*32);
            const f16x8* tpB = (const f16x8*)(tbl + (iB*4 + q4)*32);
            union U8 { f16x8 v; f16x2 h[4]; };
            U8 TA0; TA0.v = tpA[0]; U8 TA1; TA1.v = tpA[1];
            U8 TB0; TB0.v = tpB[0]; U8 TB1; TB1.v = tpB[1];

            _Float16 yhA = (_Float16)yA, yhB = (_Float16)yB;
            const f16x2 yvA = {yhA, yhA}, yvB = {yhB, yhB};
            union { f16x2 h[4]; f16x8 v; } a0, a1, b0, b1;
#pragma unroll
            for (int m = 0; m < 4; ++m) {
                a0.h[m] = __builtin_elementwise_max((f16x2)(B1[m]*yvA   + TA0.h[m]), zero2h);
                b0.h[m] = __builtin_elementwise_max((f16x2)(B1[m]*yvB   + TB0.h[m]), zero2h);
                a1.h[m] = __builtin_elementwise_max((f16x2)(B1[m+4]*yvA + TA1.h[m]), zero2h);
                b1.h[m] = __builtin_elementwise_max((f16x2)(B1[m+4]*yvB + TB1.h[m]), zero2h);
            }

            union { f16x4 q[4]; f16x8 o[2]; } BA, BB;
#pragma unroll
            for (int tN = 0; tN < 4; ++tN) {
                f32x4 dA = b2v[tN];
                f32x4 dB = b2v[tN];
                dA = __builtin_amdgcn_mfma_f32_16x16x32_f16(Af[tN][0], a0.v, dA, 0, 0, 0);
                dB = __builtin_amdgcn_mfma_f32_16x16x32_f16(Af[tN][0], b0.v, dB, 0, 0, 0);
                dA = __builtin_amdgcn_mfma_f32_16x16x32_f16(Af[tN][1], a1.v, dA, 0, 0, 0);
                dB = __builtin_amdgcn_mfma_f32_16x16x32_f16(Af[tN][1], b1.v, dB, 0, 0, 0);
                BA.q[tN] = __builtin_elementwise_max(pk4(dA), zero4h);
                BB.q[tN] = __builtin_elementwise_max(pk4(dB), zero4h);
            }

            f32x4 PA = C3b, PB = C3b;
            PA = __builtin_amdgcn_mfma_f32_16x16x32_f16(A3[0], BA.o[0], PA, 0, 0, 0);
            PB = __builtin_amdgcn_mfma_f32_16x16x32_f16(A3[0], BB.o[0], PB, 0, 0, 0);
            PA = __builtin_amdgcn_mfma_f32_16x16x32_f16(A3[1], BA.o[1], PA, 0, 0, 0);
            PB = __builtin_amdgcn_mfma_f32_16x16x32_f16(A3[1], BB.o[1], PB, 0, 0, 0);

            float zdwA = fmaf(PA[2], aw2, fmaf(PA[1], aw1, PA[0]*aw0));
            float zdzA = fmaf(PA[2], az2, fmaf(PA[1], az1, PA[0]*az0));
            Ysum += zdwA;
            float rA = zdwA - zdzA;
            acc = fmaf(rA, rA, acc);
            float zdwB = fmaf(PB[2], bw2, fmaf(PB[1], bw1, PB[0]*bw0));
            float zdzB = fmaf(PB[2], bz2_, fmaf(PB[1], bz1_, PB[0]*bz0_));
            Ysum += zdwB;
            float rB = zdwB - zdzB;
            acc = fmaf(rB, rB, acc);
        };

#pragma unroll 1
        for (int b = 0; b < 24; ++b) {
            int i = 4*b;
            ybatch(i);
            __builtin_amdgcn_s_waitcnt(0x0F72);   // vmcnt(2): slots i,i+1 done
            fillz(i + 4); fillz(i + 5);
            zpair(i,     ya, i + 1, yb);
            __builtin_amdgcn_s_waitcnt(0x0F72);   // slots i+2,i+3 done
            fillz(i + 6); fillz(i + 7);
            zpair(i + 2, yc, i + 3, yd);
        }
        // tail: bodies 96..99 (no more fills)
        ybatch(96);                                // flag >= 100
        __builtin_amdgcn_s_waitcnt(0x0F72);
        zpair(96, ya, 97, yb);
        __builtin_amdgcn_s_waitcnt(0x0F70);
        zpair(98, yc, 99, yd);

        // terminal: wait for q finals (flag = NSTEPS+1)
        {
            volatile int* qf = &flags[g][0];
            while (*qf < NSTEPS + 1) { }
        }
        float Fq = *(volatile float*)&ffin[g][ln15];
        float yT = *(volatile float*)&yring[g][NSTEPS][ln15];
        float Yvf = Y0v + Fq + Ysum;
        float dterm = Yvf - yT*yT;
        acc = fmaf(dterm, dterm, acc);

        float val = (q4 == 0) ? acc : 0.0f;
#pragma unroll
        for (int off = 1; off < 64; off <<= 1) val += __shfl_xor(val, off);
        if (lane == 0) atomicAdd(out, val * (1.0f / BATCH));
    } else {
        // ========== q-wave: serial y-recurrence, issue-priority boosted ==========
        __builtin_amdgcn_s_setprio(1);
        float y = y0v, Facc = 0.0f;
        f16x8 c0, c1, d0, d1;
        { const f16x8* tp = (const f16x8*)(tbl + q4*32); c0 = tp[2]; c1 = tp[3]; }

        auto qbody = [&](int j, f16x8& t0, f16x8& t1, f16x8& u0, f16x8& u1) {
            const float* sl = (const float*)&qring[g][j & 7][0];
            float nw0 = sl[ln15*3 + 0], nw1 = sl[ln15*3 + 1], nw2 = sl[ln15*3 + 2];
            int jp = j + 1; jp = (jp > NSTEPS - 1) ? NSTEPS - 1 : jp;
            { const f16x8* tp = (const f16x8*)(tbl + (jp*4 + q4)*32); u0 = tp[2]; u1 = tp[3]; }

            _Float16 yh = (_Float16)y;
            const f16x2 yv = {yh, yh};
            union U8 { f16x8 v; f16x2 h[4]; };
            U8 T0; T0.v = t0; U8 T1; T1.v = t1;
            union { f16x2 h[4]; f16x8 v; } b0, b1;
#pragma unroll
            for (int m = 0; m < 4; ++m) {
                b0.h[m] = __builtin_elementwise_max((f16x2)(B1[m]*yv   + T0.h[m]), zero2h);
                b1.h[m] = __builtin_elementwise_max((f16x2)(B1[m+4]*yv + T1.h[m]), zero2h);
            }
            union { f16x4 q[4]; f16x8 o[2]; } Bh;
#pragma unroll
            for (int tN = 0; tN < 4; ++tN) {
                f32x4 d = b2v[tN];
                d = __builtin_amdgcn_mfma_f32_16x16x32_f16(Af[tN][0], b0.v, d, 0, 0, 0);
                d = __builtin_amdgcn_mfma_f32_16x16x32_f16(Af[tN][1], b1.v, d, 0, 0, 0);
                Bh.q[tN] = __builtin_elementwise_max(pk4(d), zero4h);
            }
            f32x4 Pv = C3b;
            Pv = __builtin_amdgcn_mfma_f32_16x16x32_f16(A3[0], Bh.o[0], Pv, 0, 0, 0);
            Pv = __builtin_amdgcn_mfma_f32_16x16x32_f16(A3[1], Bh.o[1], Pv, 0, 0, 0);

            float qv = Pv[3];
            float snw = (nw0 + nw1) + nw2;
            Facc = fmaf(NHDT*qv, qv, Facc);
            y = fmaf(CSIG, snw, fmaf(qv, DT_, y));
            if (q4 == 0) *(volatile float*)&yring[g][j + 1][ln15] = y;  // bare ds_write
        };

#pragma unroll 1
        for (int jb = 0; jb < 24; ++jb) {
            int j = 4*jb;
            __builtin_amdgcn_s_waitcnt(0x0F73); fillq(j + 4);
            qbody(j,     c0, c1, d0, d1);
            __builtin_amdgcn_s_waitcnt(0x0F73); fillq(j + 5);
            qbody(j + 1, d0, d1, c0, c1);
            __builtin_amdgcn_s_waitcnt(0x0F73); fillq(j + 6);
            qbody(j + 2, c0, c1, d0, d1);
            __builtin_amdgcn_s_waitcnt(0x0F73); fillq(j + 7);
            qbody(j + 3, d0, d1, c0, c1);
            __builtin_amdgcn_s_waitcnt(0xC07F);                 // lgkmcnt(0): y writes landed
            if (lane == 0) *(volatile int*)&flags[g][0] = j + 4;
        }
        // tail 96..99 (no fills; declining vmcnt)
        __builtin_amdgcn_s_waitcnt(0x0F73);
        qbody(96, c0, c1, d0, d1);
        __builtin_amdgcn_s_waitcnt(0x0F72);
        qbody(97, d0, d1, c0, c1);
        __builtin_amdgcn_s_waitcnt(0x0F71);
        qbody(98, c0, c1, d0, d1);
        __builtin_amdgcn_s_waitcnt(0x0F70);
        qbody(99, d0, d1, c0, c1);
        __builtin_amdgcn_s_waitcnt(0xC07F);                     // y(100) landed
        if (lane == 0) *(volatile int*)&flags[g][0] = NSTEPS;

        if (q4 == 0) *(volatile float*)&ffin[g][ln15] = Facc;
        __builtin_amdgcn_s_waitcnt(0xC07F);
        if (lane == 0) *(volatile int*)&flags[g][0] = NSTEPS + 1;
    }
}

extern "C" void kernel_launch(void* const* d_in, const int* in_sizes, int n_in,
                              void* d_out, int out_size, void* d_ws, size_t ws_size,
                              hipStream_t stream)
{
    zero_out_kernel<<<1, 64, 0, stream>>>((float*)d_out);
    deepbsde_kernel<<<512, 256, 0, stream>>>(
        (const float*)d_in[0],  (const float*)d_in[1],
        (const float*)d_in[2],  (const float*)d_in[3],
        (const float*)d_in[4],  (const float*)d_in[5],
        (const float*)d_in[6],  (const float*)d_in[7],
        (const float*)d_in[8],  (const float*)d_in[9],
        (const float*)d_in[10], (const float*)d_in[11],
        (const float*)d_in[12], (const float*)d_in[13],
        (const float*)d_in[14], (const float*)d_in[15],
        (float*)d_out);
}